// Round 18
// baseline (49.205 us; speedup 1.0000x reference)
//
#include <hip/hip_runtime.h>

// Depthwise cross-correlation, B*C = 32768 planes: x[32][32] (*) k[8][8] -> out[25][25].
// softmax(weight) sums to 1.0 -> output == correlation; weight unused.
//
// Round-18: CROSS-GROUP PIPELINE. Each block processes 4 groups of PPB=4
// planes with double-buffered LDS (2 x 2512 dw = 20.1 KB -> 8 blocks/CU).
// Per iteration: LOAD(g+1) into regs (issue only, no wait) -> COMPUTE(g)
// on buf g&1 (r13's exact math: thread=(plane,ox), packed-bf16 rows,
// alignbit odd columns, dot2) -> WRITE regs into buf (g+1)&1 (vmcnt drain
// lands here, hidden under ~4us of dot2) -> barrier. Deterministic overlap
// of HBM staging with compute, replacing the statistical overlap that
// plateaued r13/r16/r17 at 44us.

#define NPLANES (128 * 256)
#define PPB 4                       // planes per group
#define NGRP 4                      // groups per block
#define RST 18                      // row stride (dwords)
#define XP  592                     // plane stride: >= 576+max_shift(12)
#define KTB (PPB * XP)              // taps base within buffer (2368)
#define KTS 36                      // taps plane stride
#define BUFDW (KTB + PPB * KTS)     // 2512 dw per buffer
#define OH 25
#define OW 25

__device__ __forceinline__ unsigned cvt_pk_bf16(float a, float b) {
    unsigned r;  // lo = bf16(a), hi = bf16(b)
    asm("v_cvt_pk_bf16_f32 %0, %1, %2" : "=v"(r) : "v"(a), "v"(b));
    return r;
}
__device__ __forceinline__ void dot2(float& acc, unsigned x2, unsigned k2) {
    asm("v_dot2_f32_bf16 %0, %1, %2, %0" : "+v"(acc) : "v"(x2), "v"(k2));
}
__device__ __forceinline__ unsigned alignb(unsigned hi, unsigned lo, unsigned sh) {
    unsigned r;  // ((hi:lo) >> sh)[31:0]; sh=0 -> lo
    asm("v_alignbit_b32 %0, %1, %2, %3" : "=v"(r) : "v"(hi), "v"(lo), "v"(sh));
    return r;
}
__device__ __forceinline__ int plane_shift(int pl) {
    const int m = pl % 3;           // bank de-correlation, even dwords
    return (m == 0) ? 0 : (m == 1) ? 12 : 8;
}

__global__ __launch_bounds__(128)
void dwxcorr_kernel(const float* __restrict__ x,
                    const float* __restrict__ kern,
                    float* __restrict__ out) {
    __shared__ unsigned ldsu[2 * BUFDW];
    const int tid = threadIdx.x;
    const int base_plane = blockIdx.x * (PPB * NGRP);   // 2048 blocks * 16 planes

    // Staging geometry: 2 x-units + 1 tap-unit per thread (PPB*64 = 256 x-units).
    const int pl0 = tid >> 6,  rh0 = tid & 63,  row0 = rh0 >> 1, half0 = rh0 & 1;
    const int u1  = tid + 128;
    const int pl1 = u1 >> 6,   rh1 = u1 & 63,   row1 = rh1 >> 1, half1 = rh1 & 1;
    const int tpl = tid >> 4,  to4 = tid & 15;          // taps: tid < 64

    float4 a0, a1, a2, a3, b0, b1, b2, b3, tp;

#define LOADX(g) do {                                                          \
        const size_t p_ = (size_t)(base_plane + (g) * PPB);                    \
        const float* g0_ = x + (p_ + pl0) * 1024 + row0 * 32 + half0 * 16;     \
        a0 = *(const float4*)(g0_ + 0);  a1 = *(const float4*)(g0_ + 4);       \
        a2 = *(const float4*)(g0_ + 8);  a3 = *(const float4*)(g0_ + 12);      \
        const float* g1_ = x + (p_ + pl1) * 1024 + row1 * 32 + half1 * 16;     \
        b0 = *(const float4*)(g1_ + 0);  b1 = *(const float4*)(g1_ + 4);       \
        b2 = *(const float4*)(g1_ + 8);  b3 = *(const float4*)(g1_ + 12);      \
        if (tid < PPB * 16)                                                    \
            tp = *((const float4*)kern + (p_ + tpl) * 16 + to4);               \
    } while (0)

#define WRITEX(buf) do {                                                       \
        unsigned* L_ = &ldsu[(buf) * BUFDW];                                   \
        unsigned* w0_ = &L_[pl0 * XP + plane_shift(pl0) + row0 * RST + half0 * 8]; \
        *(uint2*)(w0_ + 0) = make_uint2(cvt_pk_bf16(a0.x, a0.y), cvt_pk_bf16(a0.z, a0.w)); \
        *(uint2*)(w0_ + 2) = make_uint2(cvt_pk_bf16(a1.x, a1.y), cvt_pk_bf16(a1.z, a1.w)); \
        *(uint2*)(w0_ + 4) = make_uint2(cvt_pk_bf16(a2.x, a2.y), cvt_pk_bf16(a2.z, a2.w)); \
        *(uint2*)(w0_ + 6) = make_uint2(cvt_pk_bf16(a3.x, a3.y), cvt_pk_bf16(a3.z, a3.w)); \
        unsigned* w1_ = &L_[pl1 * XP + plane_shift(pl1) + row1 * RST + half1 * 8]; \
        *(uint2*)(w1_ + 0) = make_uint2(cvt_pk_bf16(b0.x, b0.y), cvt_pk_bf16(b0.z, b0.w)); \
        *(uint2*)(w1_ + 2) = make_uint2(cvt_pk_bf16(b1.x, b1.y), cvt_pk_bf16(b1.z, b1.w)); \
        *(uint2*)(w1_ + 4) = make_uint2(cvt_pk_bf16(b2.x, b2.y), cvt_pk_bf16(b2.z, b2.w)); \
        *(uint2*)(w1_ + 6) = make_uint2(cvt_pk_bf16(b3.x, b3.y), cvt_pk_bf16(b3.z, b3.w)); \
        if (tid < PPB * 16) {                                                  \
            unsigned* kb_ = &L_[KTB + tpl * KTS + to4 * 2];                    \
            kb_[0] = cvt_pk_bf16(tp.x, tp.y);                                  \
            kb_[1] = cvt_pk_bf16(tp.z, tp.w);                                  \
        }                                                                      \
    } while (0)

    // ---- Prologue: stage group 0 into buffer 0 ----
    LOADX(0);
    WRITEX(0);
    __syncthreads();

    const int pb = tid / 25;         // compute role: tids 0..99
    const int ox = tid % 25;
    const unsigned sh = (ox & 1) * 16;

#pragma unroll 1
    for (int g = 0; g < NGRP; ++g) {
        // ---- Issue next group's loads (no wait; regs a*/b*/tp refilled) ----
        if (g + 1 < NGRP) LOADX(g + 1);

        // ---- Compute group g from buffer g&1 ----
        if (pb < PPB) {
            const unsigned* L = &ldsu[(g & 1) * BUFDW];
            unsigned kt[32];
            {
                const unsigned* kp = &L[KTB + pb * KTS];
#pragma unroll
                for (int i = 0; i < 8; ++i) {
                    const uint4 q = *reinterpret_cast<const uint4*>(kp + 4 * i);
                    kt[4*i+0] = q.x; kt[4*i+1] = q.y; kt[4*i+2] = q.z; kt[4*i+3] = q.w;
                }
            }
            float acc[OH];
#pragma unroll
            for (int i = 0; i < OH; ++i) acc[i] = 0.f;

            const unsigned* xb = &L[pb * XP + plane_shift(pb) + (ox >> 1)];
#pragma unroll
            for (int r = 0; r < 32; ++r) {
                const unsigned* rp = xb + r * RST;
                const unsigned d0 = rp[0], d1 = rp[1], d2 = rp[2], d3 = rp[3], d4 = rp[4];
                const unsigned w0 = alignb(d1, d0, sh);
                const unsigned w1 = alignb(d2, d1, sh);
                const unsigned w2 = alignb(d3, d2, sh);
                const unsigned w3 = alignb(d4, d3, sh);
#pragma unroll
                for (int ky = 0; ky < 8; ++ky) {
                    const int oy = r - ky;       // compile-time with full unroll
                    if (oy >= 0 && oy < OH) {
                        dot2(acc[oy], w0, kt[ky * 4 + 0]);
                        dot2(acc[oy], w1, kt[ky * 4 + 1]);
                        dot2(acc[oy], w2, kt[ky * 4 + 2]);
                        dot2(acc[oy], w3, kt[ky * 4 + 3]);
                    }
                }
            }
            float* op = out + (size_t)(base_plane + g * PPB + pb) * (OH * OW) + ox;
#pragma unroll
            for (int oy = 0; oy < OH; ++oy) op[oy * OW] = acc[oy];
        }

        // ---- Write next group into the other buffer (vmcnt drain lands here) ----
        if (g + 1 < NGRP) WRITEX((g + 1) & 1);
        __syncthreads();
    }
#undef LOADX
#undef WRITEX
}

extern "C" void kernel_launch(void* const* d_in, const int* in_sizes, int n_in,
                              void* d_out, int out_size, void* d_ws, size_t ws_size,
                              hipStream_t stream) {
    const float* x = (const float*)d_in[0];
    const float* k = (const float*)d_in[1];
    // d_in[2] (weight) unused: softmax weights sum to exactly 1.
    float* out = (float*)d_out;
    const int nblocks = NPLANES / (PPB * NGRP);   // 2048
    dwxcorr_kernel<<<nblocks, 128, 0, stream>>>(x, k, out);
}

// Round 19
// 43.244 us; speedup vs baseline: 1.1378x; 1.1378x over previous
//
#include <hip/hip_runtime.h>

// Depthwise cross-correlation, B*C = 32768 planes: x[32][32] (*) k[8][8] -> out[25][25].
// softmax(weight) sums to 1.0 -> output == correlation; weight unused.
//
// Round-13 structure (best, 43.8us): thread = (plane, ox), one output column
// (25 outputs); single packed-bf16 copy of x in LDS; odd columns via
// v_alignbit (sh=(ox&1)*16); dot2 inner loop; PPB=8, block=256.
// Round-19 change: ODD-STRIDE BANK SURGERY (addressing constants only).
//   RST 18->17: odd row stride covers all 32 bank residues -> staging writes
//     go 4-way-conflicted (rows r,r+16 aliased) -> exactly 2 lanes/bank (free).
//     Writes become b32/write2 (odd base), reads stay scalar b32 + alignbit.
//   XP 592->555 (odd, ==11 mod 32): the 3 planes of a wave read bank spans
//     {0-12},{11-23},{22-2} -> pairwise-only overlap, no 3-way (r13's {0,28,8}
//     shifts had bank 8 3-way every row). plane_shift dropped entirely.
//   Taps base padded to 4444 (%4==0) -> uint4 tap reads stay 16B-aligned;
//     per-plane tap bases hit disjoint bank quads {28-31},{0-3},{4-7}.
//   LDS 18928 B -> 8 blocks/CU (was 7).

#define NPLANES (128 * 256)
#define PPB 8
#define RST 17                      // row stride (dwords): 16 data + 1 pad, ODD
#define XP  555                     // plane stride: odd, %32==11; data 544 + pad 11
#define KTB 4444                    // taps base: 8*555=4440 padded to %4==0
#define KTS 36                      // taps plane stride
#define LDS_DW (KTB + PPB * KTS)    // 4732 dw = 18928 B -> 8 blocks/CU
#define OH 25
#define OW 25

__device__ __forceinline__ unsigned cvt_pk_bf16(float a, float b) {
    unsigned r;  // lo = bf16(a), hi = bf16(b)
    asm("v_cvt_pk_bf16_f32 %0, %1, %2" : "=v"(r) : "v"(a), "v"(b));
    return r;
}
__device__ __forceinline__ void dot2(float& acc, unsigned x2, unsigned k2) {
    asm("v_dot2_f32_bf16 %0, %1, %2, %0" : "+v"(acc) : "v"(x2), "v"(k2));
}
__device__ __forceinline__ unsigned alignb(unsigned hi, unsigned lo, unsigned sh) {
    unsigned r;  // ((hi:lo) >> sh)[31:0]; sh=0 -> lo
    asm("v_alignbit_b32 %0, %1, %2, %3" : "=v"(r) : "v"(hi), "v"(lo), "v"(sh));
    return r;
}

__global__ __launch_bounds__(256)
void dwxcorr_kernel(const float* __restrict__ x,
                    const float* __restrict__ kern,
                    float* __restrict__ out) {
    __shared__ unsigned ldsu[LDS_DW];
    const int tid = threadIdx.x;
    const int plane0 = blockIdx.x * PPB;   // NPLANES % PPB == 0 -> no tail

    // ---- Stage x: unit = (plane, row, half-row of 16 floats) -> 8 packed dwords ----
#pragma unroll
    for (int it = 0; it < 2; ++it) {
        const int u    = tid + it * 256;   // PPB*64 = 512 units
        const int pl   = u >> 6;
        const int rh   = u & 63;
        const int row  = rh >> 1;
        const int half = rh & 1;
        const float* g = x + (size_t)(plane0 + pl) * 1024 + row * 32 + half * 16;
        const float4 v0 = *reinterpret_cast<const float4*>(g + 0);
        const float4 v1 = *reinterpret_cast<const float4*>(g + 4);
        const float4 v2 = *reinterpret_cast<const float4*>(g + 8);
        const float4 v3 = *reinterpret_cast<const float4*>(g + 12);
        unsigned A[8];
        A[0] = cvt_pk_bf16(v0.x, v0.y); A[1] = cvt_pk_bf16(v0.z, v0.w);
        A[2] = cvt_pk_bf16(v1.x, v1.y); A[3] = cvt_pk_bf16(v1.z, v1.w);
        A[4] = cvt_pk_bf16(v2.x, v2.y); A[5] = cvt_pk_bf16(v2.z, v2.w);
        A[6] = cvt_pk_bf16(v3.x, v3.y); A[7] = cvt_pk_bf16(v3.z, v3.w);
        // Odd base (555pl + 17row + 8half): scalar b32 writes, 2 lanes/bank (free).
        unsigned* base = &ldsu[pl * XP + row * RST + half * 8];
#pragma unroll
        for (int i = 0; i < 8; ++i) base[i] = A[i];
    }
    // ---- Stage taps: packed even pairs, flat (ky*8+kx)/2 order ----
    if (tid < PPB * 16) {
        const int pl = tid >> 4;
        const int o4 = tid & 15;
        const float4 v =
            *reinterpret_cast<const float4*>(kern + (size_t)(plane0 + pl) * 64 + o4 * 4);
        unsigned* kb = &ldsu[KTB + pl * KTS + o4 * 2];   // even -> 8B aligned
        kb[0] = cvt_pk_bf16(v.x, v.y);
        kb[1] = cvt_pk_bf16(v.z, v.w);
    }
    __syncthreads();

    const int pb = tid / 25;
    if (pb >= PPB) return;           // tids 200..255 idle after staging
    const int ox = tid % 25;

    // ---- Taps -> 32 packed dwords (16B-aligned uint4 reads, disjoint bank quads) ----
    unsigned kt[32];
    {
        const unsigned* kp = &ldsu[KTB + pb * KTS];
#pragma unroll
        for (int i = 0; i < 8; ++i) {
            const uint4 q = *reinterpret_cast<const uint4*>(kp + 4 * i);
            kt[4*i+0] = q.x; kt[4*i+1] = q.y; kt[4*i+2] = q.z; kt[4*i+3] = q.w;
        }
    }

    float acc[OH];
#pragma unroll
    for (int i = 0; i < OH; ++i) acc[i] = 0.f;

    // Window: 5 dwords (pairs p0..p0+4), shifted by (ox&1)*16 bits in-register.
    // ox=24 (even): d4 is the row-pad dword; w3 = alignb(d4,d3,0) = d3, unused-safe.
    const unsigned sh = (ox & 1) * 16;
    const unsigned* xb = &ldsu[pb * XP + (ox >> 1)];
#pragma unroll
    for (int r = 0; r < 32; ++r) {
        const unsigned* rp = xb + r * RST;
        const unsigned d0 = rp[0], d1 = rp[1], d2 = rp[2], d3 = rp[3], d4 = rp[4];
        const unsigned w0 = alignb(d1, d0, sh);
        const unsigned w1 = alignb(d2, d1, sh);
        const unsigned w2 = alignb(d3, d2, sh);
        const unsigned w3 = alignb(d4, d3, sh);
#pragma unroll
        for (int ky = 0; ky < 8; ++ky) {
            const int oy = r - ky;               // compile-time with full unroll
            if (oy >= 0 && oy < OH) {
                dot2(acc[oy], w0, kt[ky * 4 + 0]);
                dot2(acc[oy], w1, kt[ky * 4 + 1]);
                dot2(acc[oy], w2, kt[ky * 4 + 2]);
                dot2(acc[oy], w3, kt[ky * 4 + 3]);
            }
        }
    }

    // ---- Coalesced stores: consecutive ox lanes -> consecutive addresses ----
    float* op = out + (size_t)(plane0 + pb) * (OH * OW) + ox;
#pragma unroll
    for (int oy = 0; oy < OH; ++oy) op[oy * OW] = acc[oy];
}

extern "C" void kernel_launch(void* const* d_in, const int* in_sizes, int n_in,
                              void* d_out, int out_size, void* d_ws, size_t ws_size,
                              hipStream_t stream) {
    const float* x = (const float*)d_in[0];
    const float* k = (const float*)d_in[1];
    // d_in[2] (weight) unused: softmax weights sum to exactly 1.
    float* out = (float*)d_out;
    const int nblocks = NPLANES / PPB;   // 4096
    dwxcorr_kernel<<<nblocks, 256, 0, stream>>>(x, k, out);
}

// Round 20
// 39.998 us; speedup vs baseline: 1.2302x; 1.0812x over previous
//
#include <hip/hip_runtime.h>

// Depthwise cross-correlation, B*C = 32768 planes: x[32][32] (*) k[8][8] -> out[25][25].
// softmax(weight) sums to 1.0 -> output == correlation; weight unused.
//
// Round-20: MFMA Toeplitz formulation. One wave per plane (block 256 = 4 waves
// = PPB 4). For kernel row ky: out[oy][ox] += sum_c x[oy+ky][c] * k[ky][c-ox]
// == A(16x32: x rows 16rt+ky..+15, all 32 cols) x B(32x16 banded Toeplitz of
// kernel row ky, col tile ct). 8 ky x 2 rt x 2 ct = 32 v_mfma_f32_16x16x32_bf16
// per plane -> compute moves off the VALU (800 dot2) onto the matrix pipe.
//  - x in LDS: packed bf16 pairs, RST=20 dw/row (16B-aligned b128 A-reads,
//    2 lanes/bank), 40-row region (rows 32..39 garbage, feed only dropped
//    D-rows >= 25).
//  - taps in LDS: per (plane,ky) zero-padded dual-parity rows (24 dw E copy =
//    [0 x8, K0..K3, 0 x12], 24 dw O copy = odd-shifted pairs). Lane's B frag =
//    4-dword window at start=(s>>1)+8 (s = 8a-16ct-c), clamped into zero pads,
//    so out-of-range lanes read zeros. 2x ds_read2_b32 per frag.
//  - C/D layout (HW-verified): col=lane&15, row=(lane>>4)*4+reg.

#define NPLANES (128 * 256)
#define PPB 4                       // planes per block = waves per block
#define RST 20                      // x row stride (dwords), %4==0 for b128
#define XROWS 40                    // 32 data + 8 garbage-pad rows
#define XP (XROWS * RST)            // 800
#define TAPB (PPB * XP)             // 3200
#define TKY 48                      // per-ky tap row: 24 dw E + 24 dw O
#define TPP (8 * TKY)               // 384 dw per plane
#define LDS_DW (TAPB + PPB * TPP)   // 4736 dw = 18944 B -> 8 blocks/CU
#define OH 25
#define OW 25

typedef __attribute__((ext_vector_type(8))) short short8;    // 8 bf16 (4 VGPR)
typedef __attribute__((ext_vector_type(4))) float f32x4;     // MFMA acc
typedef __attribute__((ext_vector_type(4))) unsigned uint4v;

__device__ __forceinline__ unsigned cvt_pk_bf16(float a, float b) {
    unsigned r;  // lo = bf16(a), hi = bf16(b)
    asm("v_cvt_pk_bf16_f32 %0, %1, %2" : "=v"(r) : "v"(a), "v"(b));
    return r;
}

__global__ __launch_bounds__(256)
void dwxcorr_kernel(const float* __restrict__ x,
                    const float* __restrict__ kern,
                    float* __restrict__ out) {
    __shared__ unsigned ldsu[LDS_DW];
    const int tid = threadIdx.x;
    const int plane0 = blockIdx.x * PPB;   // NPLANES % PPB == 0 -> no tail

    // ---- Stage x: unit = one 4-dword quad (8 cols of a row); 2 units/thread.
    //      Write = aligned b128; banks (20r+4q)%32 -> 2 lanes/bank (free). ----
#pragma unroll
    for (int it = 0; it < 2; ++it) {
        const int q   = tid + it * 256;    // 512 quads: 4 planes x 32 rows x 4
        const int pl  = q >> 7;
        const int rem = q & 127;
        const int row = rem >> 2;
        const int qd  = rem & 3;
        const float* g = x + (size_t)(plane0 + pl) * 1024 + row * 32 + qd * 8;
        const float4 v0 = *reinterpret_cast<const float4*>(g + 0);
        const float4 v1 = *reinterpret_cast<const float4*>(g + 4);
        uint4v w;
        w.x = cvt_pk_bf16(v0.x, v0.y);
        w.y = cvt_pk_bf16(v0.z, v0.w);
        w.z = cvt_pk_bf16(v1.x, v1.y);
        w.w = cvt_pk_bf16(v1.z, v1.w);
        *reinterpret_cast<uint4v*>(&ldsu[pl * XP + row * RST + qd * 4]) = w;
    }
    // ---- Stage taps: thread (pl,ky) builds padded dual-parity row (12 b128) ----
    if (tid < PPB * 8) {
        const int pl = tid >> 3;
        const int ky = tid & 7;
        const float* g = kern + (size_t)(plane0 + pl) * 64 + ky * 8;
        const float4 v0 = *reinterpret_cast<const float4*>(g + 0);
        const float4 v1 = *reinterpret_cast<const float4*>(g + 4);
        const unsigned K0 = cvt_pk_bf16(v0.x, v0.y);
        const unsigned K1 = cvt_pk_bf16(v0.z, v0.w);
        const unsigned K2 = cvt_pk_bf16(v1.x, v1.y);
        const unsigned K3 = cvt_pk_bf16(v1.z, v1.w);
        const unsigned O7  = cvt_pk_bf16(0.f, v0.x);   // (tap[-1]=0, tap0)
        const unsigned O8  = cvt_pk_bf16(v0.y, v0.z);  // (tap1, tap2)
        const unsigned O9  = cvt_pk_bf16(v0.w, v1.x);  // (tap3, tap4)
        const unsigned O10 = cvt_pk_bf16(v1.y, v1.z);  // (tap5, tap6)
        const unsigned O11 = cvt_pk_bf16(v1.w, 0.f);   // (tap7, tap[8]=0)
        unsigned* tb = &ldsu[TAPB + pl * TPP + ky * TKY];
        const uint4v z = {0u, 0u, 0u, 0u};
        uint4v m;
        *reinterpret_cast<uint4v*>(tb + 0)  = z;
        *reinterpret_cast<uint4v*>(tb + 4)  = z;
        m.x = K0; m.y = K1; m.z = K2; m.w = K3;
        *reinterpret_cast<uint4v*>(tb + 8)  = m;       // E[8..11]
        *reinterpret_cast<uint4v*>(tb + 12) = z;
        *reinterpret_cast<uint4v*>(tb + 16) = z;
        *reinterpret_cast<uint4v*>(tb + 20) = z;
        *reinterpret_cast<uint4v*>(tb + 24) = z;       // O[0..3]
        m.x = 0u; m.y = 0u; m.z = 0u; m.w = O7;
        *reinterpret_cast<uint4v*>(tb + 28) = m;       // O[4..7]
        m.x = O8; m.y = O9; m.z = O10; m.w = O11;
        *reinterpret_cast<uint4v*>(tb + 32) = m;       // O[8..11]
        *reinterpret_cast<uint4v*>(tb + 36) = z;
        *reinterpret_cast<uint4v*>(tb + 40) = z;
        *reinterpret_cast<uint4v*>(tb + 44) = z;
    }
    __syncthreads();

    // ---- Compute: wave w handles plane plane0+w ----
    const int wave = tid >> 6;
    const int l    = tid & 63;
    const int c    = l & 15;          // A row offset / B-D col
    const int a    = l >> 4;          // k-block (k = 8a..8a+7)

    const unsigned* xb = &ldsu[wave * XP + 4 * a];
    const unsigned* tb = &ldsu[TAPB + wave * TPP];

    // Per-lane B window offsets (clamped into guaranteed-zero pads)
    int off0, off1;
    {
        int s = 8 * a - c;                       // ct = 0
        int st = (s >> 1) + 8;
        st = st < 0 ? 0 : (st > 20 ? 20 : st);
        off0 = (s & 1) * 24 + st;
        s = 8 * a - 16 - c;                      // ct = 1
        st = (s >> 1) + 8;
        st = st < 0 ? 0 : (st > 20 ? 20 : st);
        off1 = (s & 1) * 24 + st;
    }

    f32x4 acc00 = {0.f, 0.f, 0.f, 0.f};
    f32x4 acc01 = {0.f, 0.f, 0.f, 0.f};
    f32x4 acc10 = {0.f, 0.f, 0.f, 0.f};
    f32x4 acc11 = {0.f, 0.f, 0.f, 0.f};

#pragma unroll
    for (int ky = 0; ky < 8; ++ky) {
        // A frags: rows (16rt + ky + c), k-block a -> aligned b128
        const short8 a0 =
            *reinterpret_cast<const short8*>(xb + (ky + c) * RST);
        const short8 a1 =
            *reinterpret_cast<const short8*>(xb + (16 + ky + c) * RST);
        // B frags: 4-dword windows of padded tap row ky
        const unsigned* bp = tb + ky * TKY;
        uint4v bu0, bu1;
        bu0.x = bp[off0 + 0]; bu0.y = bp[off0 + 1];
        bu0.z = bp[off0 + 2]; bu0.w = bp[off0 + 3];
        bu1.x = bp[off1 + 0]; bu1.y = bp[off1 + 1];
        bu1.z = bp[off1 + 2]; bu1.w = bp[off1 + 3];
        const short8 b0 = __builtin_bit_cast(short8, bu0);
        const short8 b1 = __builtin_bit_cast(short8, bu1);
        acc00 = __builtin_amdgcn_mfma_f32_16x16x32_bf16(a0, b0, acc00, 0, 0, 0);
        acc01 = __builtin_amdgcn_mfma_f32_16x16x32_bf16(a0, b1, acc01, 0, 0, 0);
        acc10 = __builtin_amdgcn_mfma_f32_16x16x32_bf16(a1, b0, acc10, 0, 0, 0);
        acc11 = __builtin_amdgcn_mfma_f32_16x16x32_bf16(a1, b1, acc11, 0, 0, 0);
    }

    // ---- Stores: D[row][col], row = 4a+reg (+16 for rt1), col = c (+16 for ct1) ----
    float* op = out + (size_t)(plane0 + wave) * (OH * OW);
#pragma unroll
    for (int reg = 0; reg < 4; ++reg) {
        const int r0 = 4 * a + reg;              // 0..15
        op[r0 * OW + c] = acc00[reg];            // oy<=15, ox<=15: always valid
        if (c <= 8) op[r0 * OW + 16 + c] = acc01[reg];
        if (r0 <= 8) {
            op[(16 + r0) * OW + c] = acc10[reg];
            if (c <= 8) op[(16 + r0) * OW + 16 + c] = acc11[reg];
        }
    }
}

extern "C" void kernel_launch(void* const* d_in, const int* in_sizes, int n_in,
                              void* d_out, int out_size, void* d_ws, size_t ws_size,
                              hipStream_t stream) {
    const float* x = (const float*)d_in[0];
    const float* k = (const float*)d_in[1];
    // d_in[2] (weight) unused: softmax weights sum to exactly 1.
    float* out = (float*)d_out;
    const int nblocks = NPLANES / PPB;   // 8192
    dwxcorr_kernel<<<nblocks, 256, 0, stream>>>(x, k, out);
}